// Round 3
// baseline (251.781 us; speedup 1.0000x reference)
//
#include <hip/hip_runtime.h>
#include <math.h>

// SplineConv x2 (K=4, dim=1, degree=1, mean aggr) + ELU + log_softmax.
// R9: R8's 2x MLP gave only -2.4us -> agg1 is L2-miss-throughput-bound,
// not latency-bound (FETCH 104MB = 8 XCD x full 12.8MB table; reuse
// distance 6.4MB > 4MB per-XCD L2). Halve miss bytes: layer-1 xw table
// in fp8 e4m3 (x16 scale, folded into the mean divide), layout
// [node][cg][k][4ch] (128B/node) so a lane's two k-taps are two 4B
// dword loads in the SAME 64B line. HW cvt_pk_{fp8_f32,f32_fp8}.
// Layer-2 table stays bf16 (error hits logits directly).
// CSR build + xw2/agg2 unchanged from R8.

#define F_IN   48
#define HID    32
#define NCLS   10
#define KS     4
#define BKT_SH 8               // 256 nodes per bucket
#define TILE   4096            // edges per bucket_scatter block
#define FP8SC  16.f            // table pre-scale (entries |v|<4 -> <64 << 448)

typedef float floatx2 __attribute__((ext_vector_type(2)));

__device__ inline unsigned short f2bf(float f) {
    unsigned x = __float_as_uint(f);
    unsigned r = x + 0x7FFFu + ((x >> 16) & 1u);  // RNE
    return (unsigned short)(r >> 16);
}
__device__ inline float bf2f(unsigned short u) {
    return __uint_as_float(((unsigned)u) << 16);
}

// ---------- CSR build ----------

__global__ void bucket_hist_kernel(const int* __restrict__ ei, int* __restrict__ bcnt,
                                   int E, int NB) {
    __shared__ int lcnt[256];
    int t = threadIdx.x;
    lcnt[t] = 0;
    __syncthreads();
    int e0 = blockIdx.x * TILE;
    int n = min(TILE, E - e0);
    for (int r = 0; r < TILE / 256; ++r) {
        int i = r * 256 + t;
        if (i < n) atomicAdd(&lcnt[ei[E + e0 + i] >> BKT_SH], 1);
    }
    __syncthreads();
    if (t < NB && lcnt[t] > 0) atomicAdd(&bcnt[t], lcnt[t]);
}

__global__ void mini_scan_kernel(const int* __restrict__ bcnt, int* __restrict__ bbase,
                                 int* __restrict__ gcur, int NB) {
    __shared__ int a[256], c[256];
    int t = threadIdx.x;
    int v = (t < NB) ? bcnt[t] : 0;
    a[t] = v; c[t] = v;
    __syncthreads();
    for (int o = 1; o < 256; o <<= 1) {
        int w = (t >= o) ? a[t - o] : 0;
        __syncthreads();
        a[t] += w;
        __syncthreads();
    }
    int ex = a[t] - c[t];
    if (t < NB) { bbase[t] = ex; gcur[t] = ex; }
    if (t == 0) bbase[NB] = a[255];
}

__global__ void bucket_scatter_kernel(const int* __restrict__ ei, const float* __restrict__ ea,
                                      int* __restrict__ gcur, uint2* __restrict__ tpd,
                                      int E, int NB) {
    __shared__ unsigned spl[TILE];
    __shared__ unsigned short sdst[TILE];
    __shared__ unsigned short inv[TILE];
    __shared__ int lcnt[256], loff[256], lrank[256], gb[256];
    int t = threadIdx.x;
    lcnt[t] = 0; lrank[t] = 0;
    __syncthreads();
    int e0 = blockIdx.x * TILE;
    int n = min(TILE, E - e0);
    for (int r = 0; r < TILE / 256; ++r) {
        int i = r * 256 + t;
        if (i < n) {
            int e = e0 + i;
            int src = ei[e];
            int dst = ei[E + e];
            float u = ea[e];
            float v = u * (float)(KS - 1);
            float vf = floorf(v);
            int k0 = min(max((int)vf, 0), KS - 1);
            unsigned qf = (unsigned)((v - vf) * 16383.f + 0.5f);  // 14-bit frac
            spl[i] = (unsigned)src | ((unsigned)k0 << 16) | (qf << 18);
            sdst[i] = (unsigned short)dst;
            atomicAdd(&lcnt[dst >> BKT_SH], 1);
        }
    }
    __syncthreads();
    loff[t] = lcnt[t];
    __syncthreads();
    for (int o = 1; o < 256; o <<= 1) {
        int w = (t >= o) ? loff[t - o] : 0;
        __syncthreads();
        loff[t] += w;
        __syncthreads();
    }
    int ex = loff[t] - lcnt[t];
    __syncthreads();
    loff[t] = ex;
    if (t < NB) gb[t] = atomicAdd(&gcur[t], lcnt[t]);
    __syncthreads();
    for (int r = 0; r < TILE / 256; ++r) {
        int i = r * 256 + t;
        if (i < n) {
            int b = sdst[i] >> BKT_SH;
            int p = loff[b] + atomicAdd(&lrank[b], 1);
            inv[p] = (unsigned short)i;
        }
    }
    __syncthreads();
    for (int r = 0; r < TILE / 256; ++r) {
        int j = r * 256 + t;
        if (j < n) {
            int i = inv[j];
            int d = sdst[i];
            int b = d >> BKT_SH;
            int pos = gb[b] + (j - loff[b]);
            tpd[pos] = make_uint2(spl[i], (unsigned)d);
        }
    }
}

__global__ void node_sort_kernel(const uint2* __restrict__ tpd, const int* __restrict__ bbase,
                                 unsigned* __restrict__ spk, int* __restrict__ offs,
                                 int N, int NB) {
    __shared__ int hc[256], hs[256], hr[256];
    int b = blockIdx.x;
    int t = threadIdx.x;
    int nb0 = b << BKT_SH;
    int nb = min(256, N - nb0);
    int base = bbase[b];
    int m = bbase[b + 1] - base;
    hc[t] = 0; hr[t] = 0;
    __syncthreads();
    for (int i = t; i < m; i += 256) atomicAdd(&hc[tpd[base + i].y - nb0], 1);
    __syncthreads();
    hs[t] = hc[t];
    __syncthreads();
    for (int o = 1; o < 256; o <<= 1) {
        int w = (t >= o) ? hs[t - o] : 0;
        __syncthreads();
        hs[t] += w;
        __syncthreads();
    }
    if (t < nb) offs[nb0 + t] = base + (hs[t] - hc[t]);
    if (b == NB - 1 && t == 0) offs[N] = base + m;
    for (int i = t; i < m; i += 256) {
        uint2 rec = tpd[base + i];
        int d = rec.y - nb0;
        int p = (hs[d] - hc[d]) + atomicAdd(&hr[d], 1);
        spk[base + p] = rec.x;
    }
}

// ---------- xw tables (LDS-staged W, register-blocked) ----------

// Layer-1 table: fp8 e4m3, layout [node][cg 0..7][k 0..3][4ch] = 128B/node.
__global__ __launch_bounds__(320) void xw1_kernel(
        const float* __restrict__ X, const float* __restrict__ W,
        const float* __restrict__ R, unsigned char* __restrict__ outk,
        float* __restrict__ outr, int n) {
    __shared__ float lw[48 * 160];
    int t = threadIdx.x;
    for (int i = t; i < 48 * 160; i += 320) {
        int f = i / 160;
        int col = i - f * 160;
        lw[i] = (col < 128) ? W[(size_t)(col >> 5) * (48 * 32) + f * 32 + (col & 31)]
                            : R[f * 32 + (col - 128)];
    }
    __syncthreads();
    int g = t % 40;      // colgroup (4 cols)
    int lp = t / 40;     // local pair 0..7
    int n0 = (blockIdx.x * 8 + lp) * 2;
    if (n0 + 1 >= n) return;
    const float4* X0 = (const float4*)(X + (size_t)n0 * F_IN);
    const float4* X1 = (const float4*)(X + (size_t)(n0 + 1) * F_IN);
    float4 x0[12], x1[12];
#pragma unroll
    for (int i = 0; i < 12; ++i) { x0[i] = X0[i]; x1[i] = X1[i]; }
    const float4* lw4 = (const float4*)lw;  // lw4[f*40 + g]
    float4 a0 = {0,0,0,0}, a1 = {0,0,0,0};
#pragma unroll
    for (int fb = 0; fb < 12; ++fb) {
        float4 v0 = x0[fb], v1 = x1[fb];
#pragma unroll
        for (int j = 0; j < 4; ++j) {
            float s0 = (j == 0) ? v0.x : (j == 1) ? v0.y : (j == 2) ? v0.z : v0.w;
            float s1 = (j == 0) ? v1.x : (j == 1) ? v1.y : (j == 2) ? v1.z : v1.w;
            float4 w = lw4[(fb * 4 + j) * 40 + g];
            a0.x = fmaf(s0, w.x, a0.x); a0.y = fmaf(s0, w.y, a0.y);
            a0.z = fmaf(s0, w.z, a0.z); a0.w = fmaf(s0, w.w, a0.w);
            a1.x = fmaf(s1, w.x, a1.x); a1.y = fmaf(s1, w.y, a1.y);
            a1.z = fmaf(s1, w.z, a1.z); a1.w = fmaf(s1, w.w, a1.w);
        }
    }
    if (g < 32) {
        // cols 4g..4g+3 = (k = g>>3, channels 4*(g&7)..+3), fp8 x16 scale
        int off = (g & 7) * 16 + (g >> 3) * 4;
        unsigned q0 = __builtin_amdgcn_cvt_pk_fp8_f32(a0.x * FP8SC, a0.y * FP8SC, 0, 0);
        q0 = __builtin_amdgcn_cvt_pk_fp8_f32(a0.z * FP8SC, a0.w * FP8SC, q0, 1);
        unsigned q1 = __builtin_amdgcn_cvt_pk_fp8_f32(a1.x * FP8SC, a1.y * FP8SC, 0, 0);
        q1 = __builtin_amdgcn_cvt_pk_fp8_f32(a1.z * FP8SC, a1.w * FP8SC, q1, 1);
        *(unsigned*)(outk + (size_t)n0 * 128 + off) = q0;
        *(unsigned*)(outk + (size_t)(n0 + 1) * 128 + off) = q1;
    } else {
        int o = 4 * g - 128;
        *(float4*)(outr + (size_t)n0 * HID + o) = a0;
        *(float4*)(outr + (size_t)(n0 + 1) * HID + o) = a1;
    }
}

__global__ void xw2_kernel(const float* __restrict__ H, const float* __restrict__ W,
                           const float* __restrict__ R, unsigned short* __restrict__ outk,
                           float* __restrict__ outr, int n) {
    __shared__ float lw2[32 * 50];
    int t = threadIdx.x;
    for (int i = t; i < 32 * 50; i += 256) {
        int f = i / 50;
        int col = i - f * 50;
        lw2[i] = (col < 40) ? W[(size_t)(col / 10) * (32 * 10) + f * 10 + (col % 10)]
                            : R[f * 10 + (col - 40)];
    }
    __syncthreads();
    int total = (n / 2) * 25;
    int id = blockIdx.x * blockDim.x + t;
    if (id >= total) return;
    int p = id % 25;
    int pr = id / 25;
    int n0 = 2 * pr;
    const float4* H0 = (const float4*)(H + (size_t)n0 * HID);
    const float4* H1 = (const float4*)(H + (size_t)(n0 + 1) * HID);
    float4 h0[8], h1[8];
#pragma unroll
    for (int i = 0; i < 8; ++i) { h0[i] = H0[i]; h1[i] = H1[i]; }
    const float2* lwp = (const float2*)lw2;  // lwp[f*25 + p]
    float ax0 = 0.f, ay0 = 0.f, ax1 = 0.f, ay1 = 0.f;
#pragma unroll
    for (int fb = 0; fb < 8; ++fb) {
        float4 v0 = h0[fb], v1 = h1[fb];
#pragma unroll
        for (int j = 0; j < 4; ++j) {
            float s0 = (j == 0) ? v0.x : (j == 1) ? v0.y : (j == 2) ? v0.z : v0.w;
            float s1 = (j == 0) ? v1.x : (j == 1) ? v1.y : (j == 2) ? v1.z : v1.w;
            float2 w = lwp[(fb * 4 + j) * 25 + p];
            ax0 = fmaf(s0, w.x, ax0); ay0 = fmaf(s0, w.y, ay0);
            ax1 = fmaf(s1, w.x, ax1); ay1 = fmaf(s1, w.y, ay1);
        }
    }
    int col = 2 * p;
    if (col < KS * NCLS) {
        *(unsigned*)(outk + (size_t)n0 * (KS * NCLS) + col) =
            f2bf(ax0) | ((unsigned)f2bf(ay0) << 16);
        *(unsigned*)(outk + (size_t)(n0 + 1) * (KS * NCLS) + col) =
            f2bf(ax1) | ((unsigned)f2bf(ay1) << 16);
    } else {
        int o = col - KS * NCLS;
        *(float2*)(outr + (size_t)n0 * NCLS + o) = make_float2(ax0, ay0);
        *(float2*)(outr + (size_t)(n0 + 1) * NCLS + o) = make_float2(ax1, ay1);
    }
}

// ---------- aggregation ----------

// Decode a packed spline record -> fp8 row base (for this cg) + two tap
// offsets (both 4B-aligned dwords within the SAME 64B line) + frac.
#define DECODE8(p, bp, o0, o1, fr)                                        \
    {   int src_ = (p) & 0xFFFF;                                          \
        int k0_ = ((p) >> 16) & 3;                                        \
        int k1_ = min(k0_ + 1, KS - 1);                                   \
        fr = (float)((p) >> 18) * (1.f / 16383.f);                        \
        bp = xwk + (size_t)src_ * 128 + cg * 16;                          \
        o0 = k0_ * 4; o1 = k1_ * 4; }

__device__ inline void fma8(unsigned t0, unsigned t1, float fr, float4& a) {
    float w0 = 1.f - fr;
    floatx2 l0 = __builtin_amdgcn_cvt_pk_f32_fp8(t0, false);
    floatx2 h0 = __builtin_amdgcn_cvt_pk_f32_fp8(t0, true);
    floatx2 l1 = __builtin_amdgcn_cvt_pk_f32_fp8(t1, false);
    floatx2 h1 = __builtin_amdgcn_cvt_pk_f32_fp8(t1, true);
    a.x = fmaf(w0, l0.x, a.x); a.x = fmaf(fr, l1.x, a.x);
    a.y = fmaf(w0, l0.y, a.y); a.y = fmaf(fr, l1.y, a.y);
    a.z = fmaf(w0, h0.x, a.z); a.z = fmaf(fr, h1.x, a.z);
    a.w = fmaf(w0, h0.y, a.w); a.w = fmaf(fr, h1.y, a.w);
}

// agg1: one wave per node; lane = (slot 0..7, chgroup 0..7). Quad-unrolled:
// 32 edges (64 dword-gathers, 1 line/edge) in flight per wave.
__global__ void agg1_kernel(const unsigned char* __restrict__ xwk,
                            const float* __restrict__ xroot,
                            const int* __restrict__ offs, const unsigned* __restrict__ spk,
                            const float* __restrict__ bias, float* __restrict__ h, int n) {
    int lane = threadIdx.x & 63;
    int cg = lane & 7;       // channels 4cg..4cg+3
    int slot = lane >> 3;    // 8 edge slots
    int node = blockIdx.x * 4 + (threadIdx.x >> 6);
    if (node >= n) return;
    int beg = offs[node];
    int end = offs[node + 1];
    float4 a0 = {0, 0, 0, 0}, a1 = {0, 0, 0, 0};
    int e = beg + slot;
    while (e + 24 < end) {
        unsigned p0 = spk[e], p1 = spk[e + 8], p2 = spk[e + 16], p3 = spk[e + 24];
        const unsigned char *b0, *b1, *b2, *b3;
        int o00, o01, o10, o11, o20, o21, o30, o31;
        float f0, f1, f2, f3;
        DECODE8(p0, b0, o00, o01, f0);
        DECODE8(p1, b1, o10, o11, f1);
        DECODE8(p2, b2, o20, o21, f2);
        DECODE8(p3, b3, o30, o31, f3);
        unsigned t00 = *(const unsigned*)(b0 + o00), t01 = *(const unsigned*)(b0 + o01);
        unsigned t10 = *(const unsigned*)(b1 + o10), t11 = *(const unsigned*)(b1 + o11);
        unsigned t20 = *(const unsigned*)(b2 + o20), t21 = *(const unsigned*)(b2 + o21);
        unsigned t30 = *(const unsigned*)(b3 + o30), t31 = *(const unsigned*)(b3 + o31);
        fma8(t00, t01, f0, a0);
        fma8(t10, t11, f1, a1);
        fma8(t20, t21, f2, a0);
        fma8(t30, t31, f3, a1);
        e += 32;
    }
    while (e < end) {
        unsigned p = spk[e];
        const unsigned char* bp;
        int o0, o1;
        float f;
        DECODE8(p, bp, o0, o1, f);
        unsigned t0 = *(const unsigned*)(bp + o0), t1 = *(const unsigned*)(bp + o1);
        fma8(t0, t1, f, a0);
        e += 8;
    }
    float4 s;
    s.x = a0.x + a1.x; s.y = a0.y + a1.y; s.z = a0.z + a1.z; s.w = a0.w + a1.w;
#pragma unroll
    for (int m = 8; m < 64; m <<= 1) {   // reduce across 8 slots
        s.x += __shfl_xor(s.x, m, 64);
        s.y += __shfl_xor(s.y, m, 64);
        s.z += __shfl_xor(s.z, m, 64);
        s.w += __shfl_xor(s.w, m, 64);
    }
    if (slot == 0) {
        int deg = end - beg;
        float inv = (1.f / FP8SC) / (float)(deg > 0 ? deg : 1);  // undo x16 scale
        float4 r = *(const float4*)(xroot + (size_t)node * HID + cg * 4);
        float4 b = *(const float4*)(bias + cg * 4);
        float4 o;
        o.x = fmaf(s.x, inv, r.x + b.x);
        o.y = fmaf(s.y, inv, r.y + b.y);
        o.z = fmaf(s.z, inv, r.z + b.z);
        o.w = fmaf(s.w, inv, r.w + b.w);
        o.x = (o.x > 0.f) ? o.x : expm1f(o.x);
        o.y = (o.y > 0.f) ? o.y : expm1f(o.y);
        o.z = (o.z > 0.f) ? o.z : expm1f(o.z);
        o.w = (o.w > 0.f) ? o.w : expm1f(o.w);
        *(float4*)(h + (size_t)node * HID + cg * 4) = o;
    }
}

#define DECODE10(p, row, dk, fr)                                          \
    {   int src_ = (p) & 0xFFFF;                                          \
        int k0_ = ((p) >> 16) & 3;                                        \
        int k1_ = min(k0_ + 1, KS - 1);                                   \
        fr = (float)((p) >> 18) * (1.f / 16383.f);                        \
        row = xwk + (size_t)src_ * (KS * NCLS) + k0_ * NCLS + cc;         \
        dk = (k1_ - k0_) * NCLS; }

// agg2: one wave per node; lane = (slot 0..3, channel16). Quad-unrolled:
// 16 edges in flight per wave.
__global__ void agg2_kernel(const unsigned short* __restrict__ xwk,
                            const float* __restrict__ xroot,
                            const int* __restrict__ offs, const unsigned* __restrict__ spk,
                            const float* __restrict__ bias, float* __restrict__ out, int n) {
    int lane = threadIdx.x & 63;
    int c = lane & 15;
    int slot = lane >> 4;    // 4 edge slots
    int node = blockIdx.x * 4 + (threadIdx.x >> 6);
    if (node >= n) return;
    int cc = min(c, NCLS - 1);
    int beg = offs[node];
    int end = offs[node + 1];
    float s0 = 0.f, s1 = 0.f;
    int e = beg + slot;
    while (e + 12 < end) {
        unsigned p0 = spk[e], p1 = spk[e + 4], p2 = spk[e + 8], p3 = spk[e + 12];
        const unsigned short *r0, *r1, *r2, *r3;
        int d0, d1, d2, d3;
        float f0, f1, f2, f3;
        DECODE10(p0, r0, d0, f0);
        DECODE10(p1, r1, d1, f1);
        DECODE10(p2, r2, d2, f2);
        DECODE10(p3, r3, d3, f3);
        unsigned short a00 = r0[0], a01 = r0[d0];
        unsigned short a10 = r1[0], a11 = r1[d1];
        unsigned short a20 = r2[0], a21 = r2[d2];
        unsigned short a30 = r3[0], a31 = r3[d3];
        float x00 = bf2f(a00), x01 = bf2f(a01);
        float x10 = bf2f(a10), x11 = bf2f(a11);
        float x20 = bf2f(a20), x21 = bf2f(a21);
        float x30 = bf2f(a30), x31 = bf2f(a31);
        s0 += fmaf(f0, x01 - x00, x00);
        s1 += fmaf(f1, x11 - x10, x10);
        s0 += fmaf(f2, x21 - x20, x20);
        s1 += fmaf(f3, x31 - x30, x30);
        e += 16;
    }
    while (e < end) {
        unsigned p = spk[e];
        const unsigned short* r;
        int d;
        float f;
        DECODE10(p, r, d, f);
        float x0 = bf2f(r[0]), x1 = bf2f(r[d]);
        s0 += fmaf(f, x1 - x0, x0);
        e += 4;
    }
    float sum = s0 + s1;
    sum += __shfl_xor(sum, 16, 64);  // merge 4 slots
    sum += __shfl_xor(sum, 32, 64);
    int deg = end - beg;
    float m = sum / (float)(deg > 0 ? deg : 1);
    float logit = m + xroot[(size_t)node * NCLS + cc] + bias[cc];
    bool active = (c < NCLS);
    float mx = active ? logit : -INFINITY;
#pragma unroll
    for (int msk = 1; msk < 16; msk <<= 1) mx = fmaxf(mx, __shfl_xor(mx, msk, 16));
    float ex = active ? expf(logit - mx) : 0.f;
    float s = ex;
#pragma unroll
    for (int msk = 1; msk < 16; msk <<= 1) s += __shfl_xor(s, msk, 16);
    if (active && slot == 0) out[(size_t)node * NCLS + c] = (logit - mx) - logf(s);
}

extern "C" void kernel_launch(void* const* d_in, const int* in_sizes, int n_in,
                              void* d_out, int out_size, void* d_ws, size_t ws_size,
                              hipStream_t stream) {
    const float* x       = (const float*)d_in[0];
    const int*   ei      = (const int*)d_in[1];
    const float* ea      = (const float*)d_in[2];
    const float* W1      = (const float*)d_in[3];
    const float* root1   = (const float*)d_in[4];
    const float* bias1   = (const float*)d_in[5];
    const float* W2      = (const float*)d_in[6];
    const float* root2   = (const float*)d_in[7];
    const float* bias2   = (const float*)d_in[8];
    float* out = (float*)d_out;

    const int N = in_sizes[0] / F_IN;      // 50000
    const int E = in_sizes[2];             // 1600000
    const int NB = (N + 255) >> BKT_SH;    // 196

    char* base = (char*)d_ws;
    size_t off = 0;
    auto alloc = [&](size_t bytes) {
        char* p = base + off;
        off = (off + bytes + 255) & ~(size_t)255;
        return (void*)p;
    };
    unsigned char* xwk1 = (unsigned char*)alloc((size_t)N * 128);            // 6.4 MB fp8
    float* xr1          = (float*)alloc((size_t)N * HID * 4);                // 6.4 MB
    float* h            = (float*)alloc((size_t)N * HID * 4);                // 6.4 MB
    int* offs           = (int*)alloc(((size_t)N + 1) * 4);
    int* bcnt           = (int*)alloc((size_t)NB * 4);
    int* bbase          = (int*)alloc(((size_t)NB + 1) * 4);
    int* gcur           = (int*)alloc((size_t)NB * 4);
    unsigned* spk       = (unsigned*)alloc((size_t)E * 4);                   // 6.4 MB
    uint2* tpd          = (uint2*)xwk1;   // 12.8MB, spans xwk1+xr1 (both dead
                                          // until xw1, which runs after node_sort)
    unsigned short* xwk2 = (unsigned short*)xwk1;  // 4MB bf16, dead-after-agg1 region
    float* xr2           = xr1;
    if (ws_size < off) return;

    int ebk = (E + TILE - 1) / TILE;

    hipMemsetAsync(bcnt, 0, (size_t)NB * 4, stream);
    bucket_hist_kernel<<<ebk, 256, 0, stream>>>(ei, bcnt, E, NB);
    mini_scan_kernel<<<1, 256, 0, stream>>>(bcnt, bbase, gcur, NB);
    bucket_scatter_kernel<<<ebk, 256, 0, stream>>>(ei, ea, gcur, tpd, E, NB);
    node_sort_kernel<<<NB, 256, 0, stream>>>(tpd, bbase, spk, offs, N, NB);
    // xw1 after node_sort (tpd aliases xwk1+xr1)
    xw1_kernel<<<(N + 15) / 16, 320, 0, stream>>>(x, W1, root1, xwk1, xr1, N);
    agg1_kernel<<<(N + 3) / 4, 256, 0, stream>>>(xwk1, xr1, offs, spk, bias1, h, N);
    {
        int total = (N / 2) * 25;
        xw2_kernel<<<(total + 255) / 256, 256, 0, stream>>>(h, W2, root2, xwk2, xr2, N);
    }
    agg2_kernel<<<(N + 3) / 4, 256, 0, stream>>>(xwk2, xr2, offs, spk, bias2, out, N);
}